// Round 7
// baseline (254.466 us; speedup 1.0000x reference)
//
#include <hip/hip_runtime.h>

// ---------------------------------------------------------------------------
// MHA (GQA + RoPE, non-causal) on MI355X, bf16 MFMA pipeline, fp32 in/out.
// B=2 S=2048 D=2048 H=16 KV=4 hd=128.
// R7: fuse RoPE+scatter into GEMM1 epilogue (per-block uniform Q/K/V branch,
//     pair-partner via shfl_xor(1)); V-cols -> Vtmp, transpose_v reads Vtmp.
//     rope_scatter kernel and QKV intermediate eliminated. Vectorized
//     transpose_w (float4 in, ushort4 out). Attn = R6 (proven). GEMM2 = R6.
// ---------------------------------------------------------------------------

typedef __attribute__((ext_vector_type(8))) short short8;
typedef __attribute__((ext_vector_type(4))) float f32x4;

#define DEV static __device__ __forceinline__

#define NB 2
#define NS 2048
#define ND 2048
#define NH 16
#define NKV 4
#define HD 128
#define NQKV 3072   // H*hd + 2*KV*hd

DEV unsigned short f2bf(float f) {
  union { float f; unsigned u; } v; v.f = f;
  unsigned r = v.u + 0x7fffu + ((v.u >> 16) & 1u);   // RNE
  return (unsigned short)(r >> 16);
}
DEV float bf2f(unsigned short u) {
  union { unsigned u; float f; } v; v.u = ((unsigned)u) << 16; return v.f;
}
DEV unsigned pack2bf_rne(float a, float b) {
  return (unsigned)f2bf(a) | ((unsigned)f2bf(b) << 16);
}
DEV unsigned cvtpk(float a, float b) {             // [bf16(a) | bf16(b)<<16], 1 instr
  unsigned r;
  asm("v_cvt_pk_bf16_f32 %0, %1, %2" : "=v"(r) : "v"(a), "v"(b));
  return r;
}

// gfx950 permlane swaps: both operands are read+written.
DEV void swap32(unsigned &x, unsigned &y) {
  asm volatile("v_permlane32_swap_b32 %0, %1" : "+v"(x), "+v"(y));
}
DEV void swap16(unsigned &x, unsigned &y) {
  asm volatile("v_permlane16_swap_b32 %0, %1" : "+v"(x), "+v"(y));
}

typedef const __attribute__((address_space(1))) void* gas1_t;
typedef __attribute__((address_space(3))) void* las3_t;
DEV void gload16(const void* g, void* l) {
  __builtin_amdgcn_global_load_lds((gas1_t)g, (las3_t)l, 16, 0, 0);
}

DEV f32x4 mfma16(short8 a, short8 b, f32x4 c) {
  return __builtin_amdgcn_mfma_f32_16x16x32_bf16(a, b, c, 0, 0, 0);
}

// ---------------- prep kernels ----------------

__global__ __launch_bounds__(256) void convert_x_kernel(const float* __restrict__ x,
                                                        unsigned short* __restrict__ xb) {
  size_t i = ((size_t)blockIdx.x * 256 + threadIdx.x) * 4;
  float4 v = *(const float4*)(x + i);
  unsigned long long pack = (unsigned long long)f2bf(v.x)
                          | ((unsigned long long)f2bf(v.y) << 16)
                          | ((unsigned long long)f2bf(v.z) << 32)
                          | ((unsigned long long)f2bf(v.w) << 48);
  *(unsigned long long*)(xb + i) = pack;
}

// src [K][N] fp32 -> dst [N][K] bf16 (LDS tiled transpose, 64x64 tiles,
// float4 reads / ushort4 writes)
__global__ __launch_bounds__(256) void transpose_w_kernel(const float* __restrict__ src,
                                                          unsigned short* __restrict__ dst,
                                                          int K, int N) {
  __shared__ float tile[64][65];
  const int k0 = blockIdx.x * 64, n0 = blockIdx.y * 64;
  for (int i = threadIdx.x; i < 1024; i += 256) {
    int r = i >> 4, c4 = (i & 15) * 4;
    float4 v = *(const float4*)&src[(size_t)(k0 + r) * N + n0 + c4];
    tile[r][c4] = v.x; tile[r][c4 + 1] = v.y; tile[r][c4 + 2] = v.z; tile[r][c4 + 3] = v.w;
  }
  __syncthreads();
  for (int i = threadIdx.x; i < 1024; i += 256) {
    int rn = i >> 4, k4 = (i & 15) * 4;
    ushort4 o;
    o.x = f2bf(tile[k4][rn]);     o.y = f2bf(tile[k4 + 1][rn]);
    o.z = f2bf(tile[k4 + 2][rn]); o.w = f2bf(tile[k4 + 3][rn]);
    *(ushort4*)&dst[(size_t)(n0 + rn) * K + k0 + k4] = o;
  }
}

__global__ __launch_bounds__(256) void rope_table_kernel(float2* __restrict__ tab) {
  int t = blockIdx.x * 256 + threadIdx.x;        // S*64 = 131072
  int s = t >> 6, i = t & 63;
  float freq = powf(10000.0f, -(float)i * (1.0f / 64.0f));
  float ang = (float)s * freq;
  tab[t] = make_float2(cosf(ang), sinf(ang));
}

// Vtmp [4096][512] bf16 -> Vt [B][KV][hd][S] bf16 (transposed for PV A-frags)
__global__ __launch_bounds__(256) void transpose_v_kernel(const unsigned short* __restrict__ Vtmp,
                                                          unsigned short* __restrict__ Vt) {
  __shared__ unsigned short tile[64][65];
  const int bk = blockIdx.x, b = bk >> 2, kv = bk & 3;
  const int s0 = blockIdx.y * 64, d0 = blockIdx.z * 64;
  for (int i = threadIdx.x; i < 4096; i += 256) {
    int r = i >> 6, c = i & 63;   // r = s-offset, c = d-offset
    tile[r][c] = Vtmp[(size_t)(b * NS + s0 + r) * 512 + kv * 128 + d0 + c];
  }
  __syncthreads();
  for (int i = threadIdx.x; i < 4096; i += 256) {
    int r = i >> 6, c = i & 63;   // r = d-offset, c = s-offset
    Vt[(size_t)((b * NKV + kv) * HD + d0 + r) * NS + s0 + c] = tile[c][r];
  }
}

// ---------------- GEMM: C[M][N] = A[M][K=2048] * Bt[N][K]^T, bf16 in ----------------
// 128x128 tile, BK=64, 4 waves (2x2), T2 swizzled LDS, T1 XCD block swizzle.
// MODE 0: write fp32 C. MODE 1: fused QKV epilogue — Q/K rope'd+scattered
// (bf16), V -> Vtmp [4096][512] bf16.

template <int N, int MODE>
__global__ __launch_bounds__(256) void gemm_kernel(const unsigned short* __restrict__ A,
                                                   const unsigned short* __restrict__ Bt,
                                                   float* __restrict__ Cout,
                                                   const float2* __restrict__ tab,
                                                   unsigned short* __restrict__ Qb,
                                                   unsigned short* __restrict__ Kb,
                                                   unsigned short* __restrict__ Vtmp) {
  __shared__ unsigned short As[128 * 64];  // 16 KB
  __shared__ unsigned short Bs[128 * 64];  // 16 KB
  const int K = 2048;
  const int tid = threadIdx.x, wid = tid >> 6, lane = tid & 63;
  const int wm = wid >> 1, wn = wid & 1;

  // T1: XCD-aware bijective block swizzle (nwg % 8 == 0 for both GEMMs)
  const int nwg = gridDim.x * gridDim.y;
  const int bid = blockIdx.y * gridDim.x + blockIdx.x;
  const int swzb = (bid & 7) * (nwg >> 3) + (bid >> 3);
  const int m0 = (swzb % gridDim.x) * 128;
  const int n0 = (swzb / gridDim.x) * 128;

  f32x4 acc[4][4] = {};
  const int cl = lane & 15, hi8 = (lane >> 4) * 8;
  const int swg = (cl & 7) << 3;                 // read-side XOR swizzle (elems)

  const int srow = lane >> 3;                    // 0..7, == row&7
  const int scol = ((lane & 7) * 8) ^ (srow << 3);
  const unsigned short* PA = A + (size_t)(m0 + wid * 8 + srow) * K + scol;
  const unsigned short* PB = Bt + (size_t)(n0 + wid * 8 + srow) * K + scol;

  for (int kt = 0; kt < K; kt += 64) {
#pragma unroll
    for (int i = 0; i < 4; ++i)
      gload16(PA + (size_t)(i * 32) * K + kt, &As[i * 2048 + wid * 512]);
#pragma unroll
    for (int i = 0; i < 4; ++i)
      gload16(PB + (size_t)(i * 32) * K + kt, &Bs[i * 2048 + wid * 512]);
    __syncthreads();                   // drains vmcnt before use

    short8 af[2][4], bfr[2][4];
#pragma unroll
    for (int kk = 0; kk < 2; ++kk) {
#pragma unroll
      for (int r = 0; r < 4; ++r)
        af[kk][r] = *(const short8*)&As[(wm * 64 + r * 16 + cl) * 64 + ((kk * 32 + hi8) ^ swg)];
#pragma unroll
      for (int c = 0; c < 4; ++c)
        bfr[kk][c] = *(const short8*)&Bs[(wn * 64 + c * 16 + cl) * 64 + ((kk * 32 + hi8) ^ swg)];
    }
    __builtin_amdgcn_s_setprio(1);
#pragma unroll
    for (int kk = 0; kk < 2; ++kk)
#pragma unroll
      for (int r = 0; r < 4; ++r)
#pragma unroll
        for (int c = 0; c < 4; ++c)
          acc[r][c] = mfma16(af[kk][r], bfr[kk][c], acc[r][c]);
    __builtin_amdgcn_s_setprio(0);
    __syncthreads();
  }

  // epilogue: C row = m0 + wm*64 + r*16 + (lane>>4)*4 + j ; col = n0 + wn*64 + c*16 + cl
  if constexpr (MODE == 0) {
    float* C = Cout;
#pragma unroll
    for (int r = 0; r < 4; ++r) {
      const int row = m0 + wm * 64 + r * 16 + (lane >> 4) * 4;
#pragma unroll
      for (int c = 0; c < 4; ++c) {
        const int col = n0 + wn * 64 + c * 16 + cl;
#pragma unroll
        for (int j = 0; j < 4; ++j)
          C[(size_t)(row + j) * N + col] = acc[r][c][j];
      }
    }
  } else {
    // fused QKV epilogue. coltile 0..15 = Q head, 16..19 = K head, 20..23 = V.
    const int coltile = n0 >> 7;
    if (coltile < 20) {
      const bool isQ = (coltile < 16);
      const int hh = isQ ? coltile : (coltile - 16);
      const int heads = isQ ? NH : NKV;
      unsigned short* Dst = isQ ? Qb : Kb;
      const float qsc = 0.12751741161895452f;    // (1/sqrt(128)) * log2(e)
      const float sgn = (lane & 1) ? 1.0f : -1.0f;
#pragma unroll
      for (int r = 0; r < 4; ++r) {
        const int row0 = m0 + wm * 64 + r * 16 + (lane >> 4) * 4;
#pragma unroll
        for (int c = 0; c < 4; ++c) {
          const int d = wn * 64 + c * 16 + cl;
          const int ii = d >> 1;
          float p[4];
#pragma unroll
          for (int j = 0; j < 4; ++j) p[j] = __shfl_xor(acc[r][c][j], 1, 64);
#pragma unroll
          for (int j = 0; j < 4; ++j) {
            const int row = row0 + j;
            const int s = row & (NS - 1), bb = row >> 11;
            float2 cs = tab[s * 64 + ii];
            float o = acc[r][c][j] * cs.x + p[j] * cs.y * sgn;
            if (isQ) o *= qsc;
            Dst[((size_t)(bb * heads + hh) * NS + s) * HD + d] = f2bf(o);
          }
        }
      }
    } else {
      const int vc = (coltile - 20) * 128;
#pragma unroll
      for (int r = 0; r < 4; ++r) {
        const int row0 = m0 + wm * 64 + r * 16 + (lane >> 4) * 4;
#pragma unroll
        for (int c = 0; c < 4; ++c) {
          const int d = wn * 64 + c * 16 + cl;
#pragma unroll
          for (int j = 0; j < 4; ++j)
            Vtmp[(size_t)(row0 + j) * 512 + vc + d] = f2bf(acc[r][c][j]);
        }
      }
    }
  }
}

// ---------------- flash attention (non-causal, GQA) — R6 proven ----------------
// grid = 512 blocks; 4 waves, 32 q-rows/wave (2 q-frags); KVBLK=64,
// K+V double-buffered in LDS, counted vmcnt(8) prefetch, 2 barriers.
// SWAPPED QK^T -> P[k][q] lane-local; in-register P redistribution
// (cvt_pk + permlane32/16 swaps). Scores in log2 units; softmax = exp2.
// Defer-max (T13) THR=8.

__global__ __launch_bounds__(256, 2) void attn_kernel(const unsigned short* __restrict__ Qb,
                                                      const unsigned short* __restrict__ Kb,
                                                      const unsigned short* __restrict__ Vt,
                                                      unsigned short* __restrict__ O) {
  __shared__ unsigned short Ks[2][64 * 128];   // 32 KB
  __shared__ unsigned short Vs[2][128 * 64];   // 32 KB
  const int tid = threadIdx.x, wid = tid >> 6, lane = tid & 63;
  const int blk = blockIdx.x;
  const int qt = blk & 15, h = (blk >> 4) & 15, b = blk >> 8;
  const int kvh = h >> 2;
  const int q0 = qt * 128 + wid * 32;

  const unsigned short* qhead = Qb + (size_t)((b * NH + h) * NS) * HD;
  const unsigned short* khead = Kb + (size_t)((b * NKV + kvh) * NS) * HD;
  const unsigned short* vhead = Vt + (size_t)((b * NKV + kvh) * HD) * NS;

  const int cl = lane & 15, g4 = (lane >> 4) * 4, hi8 = (lane >> 4) * 8;
  const int swk = (lane & 7) << 3;

  auto stageKV = [&](int buf, int kt) {
#pragma unroll
    for (int i = 0; i < 4; ++i) {
      int row = i * 16 + (tid >> 4);
      int col = ((tid & 15) * 8) ^ ((row & 7) << 3);
      gload16(khead + (size_t)(kt + row) * HD + col, &Ks[buf][i * 2048 + wid * 512]);
    }
#pragma unroll
    for (int i = 0; i < 4; ++i) {
      int row = i * 32 + (tid >> 3);
      int col = ((tid & 7) * 8) ^ ((row & 7) << 3);
      gload16(vhead + (size_t)row * NS + kt + col, &Vs[buf][i * 2048 + wid * 512]);
    }
  };

  stageKV(0, 0);   // prologue prefetch (in flight during qf loads)

  short8 qf[2][4];
#pragma unroll
  for (int r = 0; r < 2; ++r)
#pragma unroll
    for (int kk = 0; kk < 4; ++kk)
      qf[r][kk] = *(const short8*)(qhead + (size_t)(q0 + r * 16 + cl) * HD + kk * 32 + hi8);

  f32x4 od[2][8] = {};
  float mrun[2] = {-1e30f, -1e30f}, lpart[2] = {0.f, 0.f};

  int cur = 0;
  for (int it = 0; it < NS / 64; ++it) {
    // prefetch next tile, then wait only for the CURRENT tile's 8 loads
    if (it + 1 < NS / 64) {
      stageKV(cur ^ 1, (it + 1) * 64);
      asm volatile("s_waitcnt vmcnt(8)" ::: "memory");
    } else {
      asm volatile("s_waitcnt vmcnt(0)" ::: "memory");
    }
    __builtin_amdgcn_s_barrier();      // current tile visible to all waves

    const unsigned short* ks = Ks[cur];
    const unsigned short* vs = Vs[cur];

    // ---- swapped QK^T: s[r][c4][j] = P[k = c4*16 + g4 + j][q = q0+16r+cl] ----
    f32x4 s[2][4];
#pragma unroll
    for (int r = 0; r < 2; ++r)
#pragma unroll
      for (int c4 = 0; c4 < 4; ++c4) s[r][c4] = f32x4{0.f, 0.f, 0.f, 0.f};
    __builtin_amdgcn_s_setprio(1);
#pragma unroll
    for (int c4 = 0; c4 < 4; ++c4)
#pragma unroll
      for (int kk = 0; kk < 4; ++kk) {
        short8 kf = *(const short8*)&ks[((c4 * 16 + cl) * 128 + kk * 32 + hi8) ^ swk];
        s[0][c4] = mfma16(kf, qf[0][kk], s[0][c4]);
        s[1][c4] = mfma16(kf, qf[1][kk], s[1][c4]);
      }
    __builtin_amdgcn_s_setprio(0);

    // ---- online softmax (log2 domain): k is lane-local, q = cl fixed ----
    float mt[2];
#pragma unroll
    for (int r = 0; r < 2; ++r) {
      float m = fmaxf(fmaxf(fmaxf(s[r][0][0], s[r][0][1]), fmaxf(s[r][0][2], s[r][0][3])),
                      fmaxf(fmaxf(s[r][1][0], s[r][1][1]), fmaxf(s[r][1][2], s[r][1][3])));
      float m2 = fmaxf(fmaxf(fmaxf(s[r][2][0], s[r][2][1]), fmaxf(s[r][2][2], s[r][2][3])),
                       fmaxf(fmaxf(s[r][3][0], s[r][3][1]), fmaxf(s[r][3][2], s[r][3][3])));
      m = fmaxf(m, m2);
      m = fmaxf(m, __shfl_xor(m, 16, 64));
      m = fmaxf(m, __shfl_xor(m, 32, 64));
      mt[r] = m;
    }
    bool need = (mt[0] > mrun[0] + 8.0f) || (mt[1] > mrun[1] + 8.0f);
    if (__any(need)) {
#pragma unroll
      for (int r = 0; r < 2; ++r) {
        float mn = fmaxf(mrun[r], mt[r]);
        float corr = __builtin_amdgcn_exp2f(mrun[r] - mn);
        mrun[r] = mn;
        lpart[r] *= corr;
#pragma unroll
        for (int c = 0; c < 8; ++c)
          od[r][c] *= corr;
      }
    }
#pragma unroll
    for (int r = 0; r < 2; ++r) {
      float acc = 0.f;
#pragma unroll
      for (int c4 = 0; c4 < 4; ++c4)
#pragma unroll
        for (int j = 0; j < 4; ++j) {
          float p = __builtin_amdgcn_exp2f(s[r][c4][j] - mrun[r]);
          s[r][c4][j] = p;
          acc += p;
        }
      lpart[r] += acc;
    }

    // ---- pack P to bf16 pairs (cvt_pk) and redistribute to PV B-frags ----
    short8 pb[2][2];
#pragma unroll
    for (int r = 0; r < 2; ++r) {
      unsigned w00 = cvtpk(s[r][0][0], s[r][0][1]), w01 = cvtpk(s[r][0][2], s[r][0][3]);
      unsigned w10 = cvtpk(s[r][1][0], s[r][1][1]), w11 = cvtpk(s[r][1][2], s[r][1][3]);
      unsigned w20 = cvtpk(s[r][2][0], s[r][2][1]), w21 = cvtpk(s[r][2][2], s[r][2][3]);
      unsigned w30 = cvtpk(s[r][3][0], s[r][3][1]), w31 = cvtpk(s[r][3][2], s[r][3][3]);
      union { unsigned u[4]; short8 v; } t0, t1;
      swap32(w00, w10); swap16(w00, w10); t0.u[0] = w00; t0.u[2] = w10;
      swap32(w01, w11); swap16(w01, w11); t0.u[1] = w01; t0.u[3] = w11;
      swap32(w20, w30); swap16(w20, w30); t1.u[0] = w20; t1.u[2] = w30;
      swap32(w21, w31); swap16(w21, w31); t1.u[1] = w21; t1.u[3] = w31;
      pb[r][0] = t0.v;   // k 0..31
      pb[r][1] = t1.v;   // k 32..63
    }

    // ---- PV (swapped): od[r][c] += V^T-block(c) @ P-frag; V frags shared ----
    __builtin_amdgcn_s_setprio(1);
#pragma unroll
    for (int c = 0; c < 8; ++c) {
      const int rr = c * 16 + cl;   // d-row in Vs
      short8 vf0 = *(const short8*)&vs[(rr * 64 + hi8) ^ swk];
      short8 vf1 = *(const short8*)&vs[(rr * 64 + 32 + hi8) ^ swk];
      od[0][c] = mfma16(vf0, pb[0][0], od[0][c]);
      od[0][c] = mfma16(vf1, pb[0][1], od[0][c]);
      od[1][c] = mfma16(vf0, pb[1][0], od[1][c]);
      od[1][c] = mfma16(vf1, pb[1][1], od[1][c]);
    }
    __builtin_amdgcn_s_setprio(0);
    __builtin_amdgcn_s_barrier();      // all waves done reading cur before overwrite
    cur ^= 1;
  }

  // ---- finalize: cross-group l-sum + packed 8B stores ----
  float linv[2];
#pragma unroll
  for (int r = 0; r < 2; ++r) {
    float l = lpart[r];
    l += __shfl_xor(l, 16, 64);
    l += __shfl_xor(l, 32, 64);
    linv[r] = 1.0f / l;
  }
#pragma unroll
  for (int r = 0; r < 2; ++r) {
    const size_t row = (size_t)(b * NS + q0 + 16 * r + cl);
#pragma unroll
    for (int c = 0; c < 8; ++c) {
      uint2 pk;
      pk.x = pack2bf_rne(od[r][c][0] * linv[r], od[r][c][1] * linv[r]);
      pk.y = pack2bf_rne(od[r][c][2] * linv[r], od[r][c][3] * linv[r]);
      *(uint2*)(O + row * ND + h * HD + c * 16 + g4) = pk;
    }
  }
}

// ---------------- launch ----------------

extern "C" void kernel_launch(void* const* d_in, const int* in_sizes, int n_in,
                              void* d_out, int out_size, void* d_ws, size_t ws_size,
                              hipStream_t stream) {
  const float* x  = (const float*)d_in[0];
  const float* wq = (const float*)d_in[1];
  const float* wk = (const float*)d_in[2];
  const float* wv = (const float*)d_in[3];
  const float* wo = (const float*)d_in[4];
  float* out = (float*)d_out;
  char* ws = (char*)d_ws;

  // ws layout (bytes); total = 59,768,832
  unsigned short* xb   = (unsigned short*)(ws + 0);          // 16.8 MB [4096][2048] bf16
  unsigned short* wT   = (unsigned short*)(ws + 16777216);   // 12.6 MB [3072][2048] bf16
  float2*         tab  = (float2*)(ws + 29360128);           //  1.0 MB [2048][64] cos/sin
  unsigned short* Qb   = (unsigned short*)(ws + 30408704);   // 16.8 MB [B][H][S][hd]
  unsigned short* Kb   = (unsigned short*)(ws + 47185920);   //  4.2 MB [B][KV][S][hd]
  unsigned short* Vtmp = (unsigned short*)(ws + 51380224);   //  4.2 MB [4096][512]
  unsigned short* Vt   = (unsigned short*)(ws + 55574528);   //  4.2 MB [B][KV][hd][S]
  unsigned short* woT  = wT;                                 // alias: wT dead after GEMM1
  unsigned short* Obuf = xb;                                 // alias: xb dead after GEMM1

  convert_x_kernel<<<8192, 256, 0, stream>>>(x, xb);
  transpose_w_kernel<<<dim3(32, 32), 256, 0, stream>>>(wq, wT, 2048, 2048);
  transpose_w_kernel<<<dim3(32, 8),  256, 0, stream>>>(wk, wT + (size_t)2048 * 2048, 2048, 512);
  transpose_w_kernel<<<dim3(32, 8),  256, 0, stream>>>(wv, wT + (size_t)2560 * 2048, 2048, 512);
  rope_table_kernel<<<512, 256, 0, stream>>>(tab);

  // GEMM1 with fused rope/scatter epilogue: Q->Qb, K->Kb, V->Vtmp
  gemm_kernel<NQKV, 1><<<dim3(32, 24), 256, 0, stream>>>(xb, wT, nullptr, tab, Qb, Kb, Vtmp);

  transpose_w_kernel<<<dim3(32, 32), 256, 0, stream>>>(wo, woT, 2048, 2048);  // wT dead
  transpose_v_kernel<<<dim3(8, 32, 2), 256, 0, stream>>>(Vtmp, Vt);

  attn_kernel<<<512, 256, 0, stream>>>(Qb, Kb, Vt, Obuf);

  gemm_kernel<ND, 0><<<dim3(32, 16), 256, 0, stream>>>(Obuf, woT, out, nullptr, nullptr, nullptr, nullptr);
}

// Round 8
// 243.425 us; speedup vs baseline: 1.0454x; 1.0454x over previous
//
#include <hip/hip_runtime.h>

// ---------------------------------------------------------------------------
// MHA (GQA + RoPE, non-causal) on MI355X, bf16 MFMA pipeline, fp32 in/out.
// B=2 S=2048 D=2048 H=16 KV=4 hd=128.
// R8: GEMMs -> 256x256 tile, BK=64, 8 waves, 8-phase counted-vmcnt schedule
//     (T3+T4): K-sliced half-tiles staged 1/phase (2 loads/thread),
//     vmcnt(6)+barrier per phase (sound: phase j consumes exactly the halves
//     guaranteed by its own wait), 16 MFMA/phase under setprio (T5),
//     k-major XOR-swizzled LDS (T2, 4-way residual). 128 KB LDS, 1 block/CU.
//     Prep chain reverted to R6 (separate rope_scatter; no fused epilogue).
//     Attn unchanged (R6 proven).
// ---------------------------------------------------------------------------

typedef __attribute__((ext_vector_type(8))) short short8;
typedef __attribute__((ext_vector_type(4))) float f32x4;

#define DEV static __device__ __forceinline__

#define NB 2
#define NS 2048
#define ND 2048
#define NH 16
#define NKV 4
#define HD 128
#define NQKV 3072   // H*hd + 2*KV*hd

DEV unsigned short f2bf(float f) {
  union { float f; unsigned u; } v; v.f = f;
  unsigned r = v.u + 0x7fffu + ((v.u >> 16) & 1u);   // RNE
  return (unsigned short)(r >> 16);
}
DEV float bf2f(unsigned short u) {
  union { unsigned u; float f; } v; v.u = ((unsigned)u) << 16; return v.f;
}
DEV unsigned pack2bf_rne(float a, float b) {
  return (unsigned)f2bf(a) | ((unsigned)f2bf(b) << 16);
}
DEV unsigned cvtpk(float a, float b) {             // [bf16(a) | bf16(b)<<16], 1 instr
  unsigned r;
  asm("v_cvt_pk_bf16_f32 %0, %1, %2" : "=v"(r) : "v"(a), "v"(b));
  return r;
}

// gfx950 permlane swaps: both operands are read+written.
DEV void swap32(unsigned &x, unsigned &y) {
  asm volatile("v_permlane32_swap_b32 %0, %1" : "+v"(x), "+v"(y));
}
DEV void swap16(unsigned &x, unsigned &y) {
  asm volatile("v_permlane16_swap_b32 %0, %1" : "+v"(x), "+v"(y));
}

typedef const __attribute__((address_space(1))) void* gas1_t;
typedef __attribute__((address_space(3))) void* las3_t;
DEV void gload16(const void* g, void* l) {
  __builtin_amdgcn_global_load_lds((gas1_t)g, (las3_t)l, 16, 0, 0);
}

DEV f32x4 mfma16(short8 a, short8 b, f32x4 c) {
  return __builtin_amdgcn_mfma_f32_16x16x32_bf16(a, b, c, 0, 0, 0);
}

// ---------------- prep kernels ----------------

__global__ __launch_bounds__(256) void convert_x_kernel(const float* __restrict__ x,
                                                        unsigned short* __restrict__ xb) {
  size_t i = ((size_t)blockIdx.x * 256 + threadIdx.x) * 4;
  float4 v = *(const float4*)(x + i);
  unsigned long long pack = (unsigned long long)f2bf(v.x)
                          | ((unsigned long long)f2bf(v.y) << 16)
                          | ((unsigned long long)f2bf(v.z) << 32)
                          | ((unsigned long long)f2bf(v.w) << 48);
  *(unsigned long long*)(xb + i) = pack;
}

// src [K][N] fp32 -> dst [N][K] bf16 (LDS tiled transpose, 64x64 tiles,
// float4 reads / ushort4 writes)
__global__ __launch_bounds__(256) void transpose_w_kernel(const float* __restrict__ src,
                                                          unsigned short* __restrict__ dst,
                                                          int K, int N) {
  __shared__ float tile[64][65];
  const int k0 = blockIdx.x * 64, n0 = blockIdx.y * 64;
  for (int i = threadIdx.x; i < 1024; i += 256) {
    int r = i >> 4, c4 = (i & 15) * 4;
    float4 v = *(const float4*)&src[(size_t)(k0 + r) * N + n0 + c4];
    tile[r][c4] = v.x; tile[r][c4 + 1] = v.y; tile[r][c4 + 2] = v.z; tile[r][c4 + 3] = v.w;
  }
  __syncthreads();
  for (int i = threadIdx.x; i < 1024; i += 256) {
    int rn = i >> 4, k4 = (i & 15) * 4;
    ushort4 o;
    o.x = f2bf(tile[k4][rn]);     o.y = f2bf(tile[k4 + 1][rn]);
    o.z = f2bf(tile[k4 + 2][rn]); o.w = f2bf(tile[k4 + 3][rn]);
    *(ushort4*)&dst[(size_t)(n0 + rn) * K + k0 + k4] = o;
  }
}

__global__ __launch_bounds__(256) void rope_table_kernel(float2* __restrict__ tab) {
  int t = blockIdx.x * 256 + threadIdx.x;        // S*64 = 131072
  int s = t >> 6, i = t & 63;
  float freq = powf(10000.0f, -(float)i * (1.0f / 64.0f));
  float ang = (float)s * freq;
  tab[t] = make_float2(cosf(ang), sinf(ang));
}

// QKV [4096][3072] bf16 -> Qb [B][H][S][hd] (rope, *log2e/sqrt(hd)), Kb (rope)
__global__ __launch_bounds__(256) void rope_scatter_kernel(const unsigned short* __restrict__ QKV,
                                                           const float2* __restrict__ tab,
                                                           unsigned short* __restrict__ Qb,
                                                           unsigned short* __restrict__ Kb) {
  int t = blockIdx.x * 256 + threadIdx.x;
  const float qscale = 0.12751741161895452f;     // (1/sqrt(128)) * log2(e)
  if (t < (1 << 22)) {                           // Q pairs: B*S*H*64 = 2^22
    int i = t & 63, h = (t >> 6) & 15, s = (t >> 10) & 2047, b = t >> 21;
    const unsigned short* p = QKV + (size_t)(b * NS + s) * NQKV + h * HD + 2 * i;
    float2 cs = tab[s * 64 + i];
    float x1 = bf2f(p[0]), x2 = bf2f(p[1]);
    unsigned short* q = Qb + (size_t)((b * NH + h) * NS + s) * HD + 2 * i;
    q[0] = f2bf((x1 * cs.x - x2 * cs.y) * qscale);
    q[1] = f2bf((x1 * cs.y + x2 * cs.x) * qscale);
  } else {                                       // K pairs: B*S*KV*64 = 2^20
    int u = t - (1 << 22);
    int i = u & 63, kv = (u >> 6) & 3, s = (u >> 8) & 2047, b = u >> 19;
    const unsigned short* p = QKV + (size_t)(b * NS + s) * NQKV + 2048 + kv * HD + 2 * i;
    float2 cs = tab[s * 64 + i];
    float x1 = bf2f(p[0]), x2 = bf2f(p[1]);
    unsigned short* k = Kb + (size_t)((b * NKV + kv) * NS + s) * HD + 2 * i;
    k[0] = f2bf(x1 * cs.x - x2 * cs.y);
    k[1] = f2bf(x1 * cs.y + x2 * cs.x);
  }
}

// V columns of QKV -> Vt [B][KV][hd][S] bf16 (transposed for PV A-fragments)
__global__ __launch_bounds__(256) void transpose_v_kernel(const unsigned short* __restrict__ QKV,
                                                          unsigned short* __restrict__ Vt) {
  __shared__ unsigned short tile[64][65];
  const int bk = blockIdx.x, b = bk >> 2, kv = bk & 3;
  const int s0 = blockIdx.y * 64, d0 = blockIdx.z * 64;
  for (int i = threadIdx.x; i < 4096; i += 256) {
    int r = i >> 6, c = i & 63;   // r = s-offset, c = d-offset
    tile[r][c] = QKV[(size_t)(b * NS + s0 + r) * NQKV + 2560 + kv * HD + d0 + c];
  }
  __syncthreads();
  for (int i = threadIdx.x; i < 4096; i += 256) {
    int r = i >> 6, c = i & 63;   // r = d-offset, c = s-offset
    Vt[(size_t)((b * NKV + kv) * HD + d0 + r) * NS + s0 + c] = tile[c][r];
  }
}

// ---------------- GEMM 256x256, 8-phase counted-vmcnt (T2+T3+T4+T5) ----------------
// C[M][N] = A[M][K=2048] * Bt[N][K]^T, bf16 in, fp32 acc.
// 8 waves (2M x 4N), per-wave C = 128x64 = acc[8][4].
// LDS: Sm[buf][op][khalf][256 rows][32 elems] (k-major), 128 KB total.
// Swizzle: elem col ^= (row&3)<<3 (stage source pre-swizzled; reads XOR'd).
// Half-tiles per K-tile: h0=A.k0, h1=B.k0, h2=A.k1, h3=B.k1 (16 KB each,
// 2 gload16/thread). Phase j of tile t stages half j of tile t+1, then
// vmcnt(6)+barrier — guarantees exactly the halves phase j consumes:
//   p0: reads A.k0 (cov. prev tile p3) + B.k0 (cov. THIS wait)
//   p1: reads B.k0 (already cov.)
//   p2: reads A.k1 + B.k1 (A.k1 cov. p1's wait; B.k1 cov. THIS wait)
//   p3: reads B.k1 (already cov.)
// Buffer swap hazard gated by the end-of-tile barrier. Tail tile: vmcnt(0).

template <int N, bool OUTBF16>
__global__ __launch_bounds__(512) void gemm256_kernel(const unsigned short* __restrict__ A,
                                                      const unsigned short* __restrict__ Bt,
                                                      void* __restrict__ Cout) {
  __shared__ unsigned short Sm[2][2][2][256 * 32];   // 128 KB
  const int K = 2048, NT = K / 64;
  const int tid = threadIdx.x, wid = tid >> 6, lane = tid & 63;
  const int wm = wid >> 2, wn = wid & 3;

  // T1: XCD-aware bijective block swizzle (nwg % 8 == 0 for both GEMMs)
  const int nwg = gridDim.x * gridDim.y;
  const int bid = blockIdx.y * gridDim.x + blockIdx.x;
  const int swzb = (bid & 7) * (nwg >> 3) + (bid >> 3);
  const int m0 = (swzb % gridDim.x) * 256;
  const int n0 = (swzb / gridDim.x) * 256;

  const int cl = lane & 15, g = lane >> 4;
  const int rsw = (cl & 3) << 3;                 // read-side swizzle (elems)

  // staging map: thread -> row tid>>2 (+128 round 2), col (tid&3)*8 pre-swizzled
  const int stg_row = tid >> 2;
  const int stg_colE = ((tid & 3) * 8) ^ ((stg_row & 3) << 3);
  const unsigned short* Abase = A + (size_t)(m0 + stg_row) * K + stg_colE;
  const unsigned short* Bbase = Bt + (size_t)(n0 + stg_row) * K + stg_colE;

  // stage half h (0=A.k0 1=B.k0 2=A.k1 3=B.k1) of K-tile at kt into buf
  auto stage_half = [&](int buf, int kt, int h) {
    const int op = h & 1, kh = h >> 1;
    const unsigned short* s0 = (op ? Bbase : Abase) + kt + kh * 32;
    unsigned short* dst = &Sm[buf][op][kh][wid * 512];
    gload16(s0, dst);
    gload16(s0 + (size_t)128 * K, dst + 4096);
  };

  auto read_a = [&](int buf, int kh, int r) -> short8 {
    const int row = wm * 128 + r * 16 + cl;      // row&3 == cl&3
    return *(const short8*)&Sm[buf][0][kh][row * 32 + ((g * 8) ^ rsw)];
  };
  auto read_b = [&](int buf, int kh, int cf) -> short8 {
    const int row = wn * 64 + cf * 16 + cl;
    return *(const short8*)&Sm[buf][1][kh][row * 32 + ((g * 8) ^ rsw)];
  };

  f32x4 acc[8][4] = {};
  short8 af[8];

  // prologue: stage tile 0 fully (8 loads/thread)
#pragma unroll
  for (int h = 0; h < 4; ++h) stage_half(0, 0, h);

  for (int t = 0; t < NT - 1; ++t) {
    const int buf = t & 1, ktn = (t + 1) * 64;
#pragma unroll
    for (int ph = 0; ph < 4; ++ph) {
      stage_half(buf ^ 1, ktn, ph);
      asm volatile("s_waitcnt vmcnt(6)" ::: "memory");
      __builtin_amdgcn_s_barrier();
      const int kh = ph >> 1, ch = ph & 1;
      if (ch == 0) {
#pragma unroll
        for (int r = 0; r < 8; ++r) af[r] = read_a(buf, kh, r);
      }
      short8 b0 = read_b(buf, kh, ch * 2);
      short8 b1 = read_b(buf, kh, ch * 2 + 1);
      __builtin_amdgcn_s_setprio(1);
#pragma unroll
      for (int r = 0; r < 8; ++r) {
        acc[r][ch * 2]     = mfma16(af[r], b0, acc[r][ch * 2]);
        acc[r][ch * 2 + 1] = mfma16(af[r], b1, acc[r][ch * 2 + 1]);
      }
      __builtin_amdgcn_s_setprio(0);
      __builtin_amdgcn_s_barrier();
    }
  }

  // tail tile: everything staged; drain and compute
  asm volatile("s_waitcnt vmcnt(0)" ::: "memory");
  __builtin_amdgcn_s_barrier();
  {
    const int buf = (NT - 1) & 1;
#pragma unroll
    for (int kh = 0; kh < 2; ++kh) {
#pragma unroll
      for (int r = 0; r < 8; ++r) af[r] = read_a(buf, kh, r);
#pragma unroll
      for (int cf = 0; cf < 4; ++cf) {
        short8 b = read_b(buf, kh, cf);
#pragma unroll
        for (int r = 0; r < 8; ++r) acc[r][cf] = mfma16(af[r], b, acc[r][cf]);
      }
    }
  }

  // epilogue: row = m0 + wm*128 + r*16 + g*4 + j ; col = n0 + wn*64 + cf*16 + cl
  if (OUTBF16) {
    unsigned short* C = (unsigned short*)Cout;
#pragma unroll
    for (int r = 0; r < 8; ++r) {
      const int row0 = m0 + wm * 128 + r * 16 + g * 4;
#pragma unroll
      for (int cf = 0; cf < 4; ++cf) {
        const int col = n0 + wn * 64 + cf * 16 + cl;
#pragma unroll
        for (int j = 0; j < 4; ++j)
          C[(size_t)(row0 + j) * N + col] = f2bf(acc[r][cf][j]);
      }
    }
  } else {
    float* C = (float*)Cout;
#pragma unroll
    for (int r = 0; r < 8; ++r) {
      const int row0 = m0 + wm * 128 + r * 16 + g * 4;
#pragma unroll
      for (int cf = 0; cf < 4; ++cf) {
        const int col = n0 + wn * 64 + cf * 16 + cl;
#pragma unroll
        for (int j = 0; j < 4; ++j)
          C[(size_t)(row0 + j) * N + col] = acc[r][cf][j];
      }
    }
  }
}

// ---------------- flash attention (non-causal, GQA) — R6 proven ----------------
// grid = 512 blocks; 4 waves, 32 q-rows/wave (2 q-frags); KVBLK=64,
// K+V double-buffered in LDS, counted vmcnt(8) prefetch, 2 barriers.
// SWAPPED QK^T -> P[k][q] lane-local; in-register P redistribution
// (cvt_pk + permlane32/16 swaps). Scores in log2 units; softmax = exp2.
// Defer-max (T13) THR=8.

__global__ __launch_bounds__(256, 2) void attn_kernel(const unsigned short* __restrict__ Qb,
                                                      const unsigned short* __restrict__ Kb,
                                                      const unsigned short* __restrict__ Vt,
                                                      unsigned short* __restrict__ O) {
  __shared__ unsigned short Ks[2][64 * 128];   // 32 KB
  __shared__ unsigned short Vs[2][128 * 64];   // 32 KB
  const int tid = threadIdx.x, wid = tid >> 6, lane = tid & 63;
  const int blk = blockIdx.x;
  const int qt = blk & 15, h = (blk >> 4) & 15, b = blk >> 8;
  const int kvh = h >> 2;
  const int q0 = qt * 128 + wid * 32;

  const unsigned short* qhead = Qb + (size_t)((b * NH + h) * NS) * HD;
  const unsigned short* khead = Kb + (size_t)((b * NKV + kvh) * NS) * HD;
  const unsigned short* vhead = Vt + (size_t)((b * NKV + kvh) * HD) * NS;

  const int cl = lane & 15, g4 = (lane >> 4) * 4, hi8 = (lane >> 4) * 8;
  const int swk = (lane & 7) << 3;

  auto stageKV = [&](int buf, int kt) {
#pragma unroll
    for (int i = 0; i < 4; ++i) {
      int row = i * 16 + (tid >> 4);
      int col = ((tid & 15) * 8) ^ ((row & 7) << 3);
      gload16(khead + (size_t)(kt + row) * HD + col, &Ks[buf][i * 2048 + wid * 512]);
    }
#pragma unroll
    for (int i = 0; i < 4; ++i) {
      int row = i * 32 + (tid >> 3);
      int col = ((tid & 7) * 8) ^ ((row & 7) << 3);
      gload16(vhead + (size_t)row * NS + kt + col, &Vs[buf][i * 2048 + wid * 512]);
    }
  };

  stageKV(0, 0);   // prologue prefetch (in flight during qf loads)

  short8 qf[2][4];
#pragma unroll
  for (int r = 0; r < 2; ++r)
#pragma unroll
    for (int kk = 0; kk < 4; ++kk)
      qf[r][kk] = *(const short8*)(qhead + (size_t)(q0 + r * 16 + cl) * HD + kk * 32 + hi8);

  f32x4 od[2][8] = {};
  float mrun[2] = {-1e30f, -1e30f}, lpart[2] = {0.f, 0.f};

  int cur = 0;
  for (int it = 0; it < NS / 64; ++it) {
    // prefetch next tile, then wait only for the CURRENT tile's 8 loads
    if (it + 1 < NS / 64) {
      stageKV(cur ^ 1, (it + 1) * 64);
      asm volatile("s_waitcnt vmcnt(8)" ::: "memory");
    } else {
      asm volatile("s_waitcnt vmcnt(0)" ::: "memory");
    }
    __builtin_amdgcn_s_barrier();      // current tile visible to all waves

    const unsigned short* ks = Ks[cur];
    const unsigned short* vs = Vs[cur];

    // ---- swapped QK^T: s[r][c4][j] = P[k = c4*16 + g4 + j][q = q0+16r+cl] ----
    f32x4 s[2][4];
#pragma unroll
    for (int r = 0; r < 2; ++r)
#pragma unroll
      for (int c4 = 0; c4 < 4; ++c4) s[r][c4] = f32x4{0.f, 0.f, 0.f, 0.f};
    __builtin_amdgcn_s_setprio(1);
#pragma unroll
    for (int c4 = 0; c4 < 4; ++c4)
#pragma unroll
      for (int kk = 0; kk < 4; ++kk) {
        short8 kf = *(const short8*)&ks[((c4 * 16 + cl) * 128 + kk * 32 + hi8) ^ swk];
        s[0][c4] = mfma16(kf, qf[0][kk], s[0][c4]);
        s[1][c4] = mfma16(kf, qf[1][kk], s[1][c4]);
      }
    __builtin_amdgcn_s_setprio(0);

    // ---- online softmax (log2 domain): k is lane-local, q = cl fixed ----
    float mt[2];
#pragma unroll
    for (int r = 0; r < 2; ++r) {
      float m = fmaxf(fmaxf(fmaxf(s[r][0][0], s[r][0][1]), fmaxf(s[r][0][2], s[r][0][3])),
                      fmaxf(fmaxf(s[r][1][0], s[r][1][1]), fmaxf(s[r][1][2], s[r][1][3])));
      float m2 = fmaxf(fmaxf(fmaxf(s[r][2][0], s[r][2][1]), fmaxf(s[r][2][2], s[r][2][3])),
                       fmaxf(fmaxf(s[r][3][0], s[r][3][1]), fmaxf(s[r][3][2], s[r][3][3])));
      m = fmaxf(m, m2);
      m = fmaxf(m, __shfl_xor(m, 16, 64));
      m = fmaxf(m, __shfl_xor(m, 32, 64));
      mt[r] = m;
    }
    bool need = (mt[0] > mrun[0] + 8.0f) || (mt[1] > mrun[1] + 8.0f);
    if (__any(need)) {
#pragma unroll
      for (int r = 0; r < 2; ++r) {
        float mn = fmaxf(mrun[r], mt[r]);
        float corr = __builtin_amdgcn_exp2f(mrun[r] - mn);
        mrun[r] = mn;
        lpart[r] *= corr;
#pragma unroll
        for (int c = 0; c < 8; ++c)
          od[r][c] *= corr;
      }
    }
#pragma unroll
    for (int r = 0; r < 2; ++r) {
      float acc = 0.f;
#pragma unroll
      for (int c4 = 0; c4 < 4; ++c4)
#pragma unroll
        for (int j = 0; j < 4; ++j) {
          float p = __builtin_amdgcn_exp2f(s[r][c4][j] - mrun[r]);
          s[r][c4][j] = p;
          acc += p;
        }
      lpart[r] += acc;
    }

    // ---- pack P to bf16 pairs (cvt_pk) and redistribute to PV B-frags ----
    short8 pb[2][2];
#pragma unroll
    for (int r = 0; r < 2; ++r) {
      unsigned w00 = cvtpk(s[r][0][0], s[r][0][1]), w01 = cvtpk(s[r][0][2], s[r][0][3]);
      unsigned w10 = cvtpk(s[r][1][0], s[r][1][1]), w11 = cvtpk(s[r][1][2], s[r][1][3]);
      unsigned w20 = cvtpk(s[r][2][0], s[r][2][1]), w21 = cvtpk(s[r][2][2], s[r][2][3]);
      unsigned w30 = cvtpk(s[r][3][0], s[r][3][1]), w31 = cvtpk(s[r][3][2], s[r][3][3]);
      union { unsigned u[4]; short8 v; } t0, t1;
      swap32(w00, w10); swap16(w00, w10); t0.u[0] = w00; t0.u[2] = w10;
      swap32(w01, w11); swap16(w01, w11); t0.u[1] = w01; t0.u[3] = w11;
      swap32(w20, w30); swap16(w20, w30); t1.u[0] = w20; t1.u[2] = w30;
      swap32(w21, w31); swap16(w21, w31); t1.u[1] = w21; t1.u[3] = w31;
      pb[r][0] = t0.v;   // k 0..31
      pb[r][1] = t1.v;   // k 32..63
    }

    // ---- PV (swapped): od[r][c] += V^T-block(c) @ P-frag; V frags shared ----
    __builtin_amdgcn_s_setprio(1);
#pragma unroll
    for (int c = 0; c < 8; ++c) {
      const int rr = c * 16 + cl;   // d-row in Vs
      short8 vf0 = *(const short8*)&vs[(rr * 64 + hi8) ^ swk];
      short8 vf1 = *(const short8*)&vs[(rr * 64 + 32 + hi8) ^ swk];
      od[0][c] = mfma16(vf0, pb[0][0], od[0][c]);
      od[0][c] = mfma16(vf1, pb[0][1], od[0][c]);
      od[1][c] = mfma16(vf0, pb[1][0], od[1][c]);
      od[1][c] = mfma16(vf1, pb[1][1], od[1][c]);
    }
    __builtin_amdgcn_s_setprio(0);
    __builtin_amdgcn_s_barrier();      // all waves done reading cur before overwrite
    cur ^= 1;
  }

  // ---- finalize: cross-group l-sum + packed 8B stores ----
  float linv[2];
#pragma unroll
  for (int r = 0; r < 2; ++r) {
    float l = lpart[r];
    l += __shfl_xor(l, 16, 64);
    l += __shfl_xor(l, 32, 64);
    linv[r] = 1.0f / l;
  }
#pragma unroll
  for (int r = 0; r < 2; ++r) {
    const size_t row = (size_t)(b * NS + q0 + 16 * r + cl);
#pragma unroll
    for (int c = 0; c < 8; ++c) {
      uint2 pk;
      pk.x = pack2bf_rne(od[r][c][0] * linv[r], od[r][c][1] * linv[r]);
      pk.y = pack2bf_rne(od[r][c][2] * linv[r], od[r][c][3] * linv[r]);
      *(uint2*)(O + row * ND + h * HD + c * 16 + g4) = pk;
    }
  }
}

// ---------------- launch ----------------

extern "C" void kernel_launch(void* const* d_in, const int* in_sizes, int n_in,
                              void* d_out, int out_size, void* d_ws, size_t ws_size,
                              hipStream_t stream) {
  const float* x  = (const float*)d_in[0];
  const float* wq = (const float*)d_in[1];
  const float* wk = (const float*)d_in[2];
  const float* wv = (const float*)d_in[3];
  const float* wo = (const float*)d_in[4];
  float* out = (float*)d_out;
  char* ws = (char*)d_ws;

  // ws layout (bytes); total needed = 63,963,136
  unsigned short* xb   = (unsigned short*)(ws + 0);          // 16.8 MB [4096][2048] bf16
  unsigned short* wT   = (unsigned short*)(ws + 16777216);   // 12.6 MB [3072][2048] bf16
  unsigned short* woT  = (unsigned short*)(ws + 29360128);   //  8.4 MB [2048][2048] bf16
  float2*         tab  = (float2*)(ws + 37748736);           //  1.0 MB [2048][64] cos/sin
  unsigned short* QKV  = (unsigned short*)(ws + 38797312);   // 25.2 MB [4096][3072] bf16
  unsigned short* Qb   = xb;                                 // alias: xb dead after GEMM1
  unsigned short* Kb   = wT;                                 // alias: wT dead after GEMM1
  unsigned short* Vt   = (unsigned short*)(ws + 16777216 + 4194304);
  unsigned short* Obuf = QKV;                                // alias: QKV dead after scatter

  convert_x_kernel<<<8192, 256, 0, stream>>>(x, xb);
  transpose_w_kernel<<<dim3(32, 32), 256, 0, stream>>>(wq, wT, 2048, 2048);
  transpose_w_kernel<<<dim3(32, 8),  256, 0, stream>>>(wk, wT + (size_t)2048 * 2048, 2048, 512);
  transpose_w_kernel<<<dim3(32, 8),  256, 0, stream>>>(wv, wT + (size_t)2560 * 2048, 2048, 512);
  transpose_w_kernel<<<dim3(32, 32), 256, 0, stream>>>(wo, woT, 2048, 2048);
  rope_table_kernel<<<512, 256, 0, stream>>>(tab);

  gemm256_kernel<NQKV, true><<<dim3(16, 12), 512, 0, stream>>>(xb, wT, QKV);

  rope_scatter_kernel<<<20480, 256, 0, stream>>>(QKV, tab, Qb, Kb);
  transpose_v_kernel<<<dim3(8, 32, 2), 256, 0, stream>>>(QKV, Vt);

  attn_kernel<<<512, 256, 0, stream>>>(Qb, Kb, Vt, Obuf);

  gemm256_kernel<ND, false><<<dim3(16, 8), 512, 0, stream>>>(Obuf, woT, out);
}